// Round 1
// baseline (411.770 us; speedup 1.0000x reference)
//
#include <hip/hip_runtime.h>
#include <math.h>

#define BB   64
#define PTS  4096
#define NTOT (BB * PTS)
#define OBS  128
#define ACT  5
#define HID  256
#define LAT  64
#define CTX  128
#define XIN  (LAT + ACT + 1)   // 70
#define LOG2PIE 2.8378770664093453f

// output offsets (floats), concat order: h, z, context, priority, priority_norm, uncertainty
#define OFF_H   0
#define OFF_Z   (BB * HID)              // 16384
#define OFF_CTX (OFF_Z + BB * LAT)      // 20480
#define OFF_PRI (OFF_CTX + BB * CTX)    // 28672
#define OFF_PN  (OFF_PRI + NTOT)        // 290816
#define OFF_UNC (OFF_PN + NTOT)         // 552960

#define CHUNKS 8                        // blocks per segment for the obs passes
#define ROWS_PER_CHUNK (PTS / CHUNKS)   // 512

// ---------------- Pass 1: obs segment sum (hot, memory-bound) ----------------
// grid = BB*CHUNKS blocks x 256 threads. Each block reduces 512 rows x 128 cols.
// Thread t: col-group c4 = t&31 (float4), row-group rg = t>>5 (8 rows in flight).
__global__ void seg_sum_kernel(const float* __restrict__ obs,
                               float* __restrict__ obs_sum) {
    int blk = blockIdx.x;
    int b = blk / CHUNKS;
    int chunk = blk % CHUNKS;
    int t = threadIdx.x;
    int c4 = t & 31;
    int rg = t >> 5;
    const float4* obs4 = (const float4*)obs;
    size_t row0 = (size_t)b * PTS + (size_t)chunk * ROWS_PER_CHUNK;
    float4 acc = make_float4(0.f, 0.f, 0.f, 0.f);
    for (int r = rg; r < ROWS_PER_CHUNK; r += 8) {
        float4 v = obs4[(row0 + r) * (OBS / 4) + c4];
        acc.x += v.x; acc.y += v.y; acc.z += v.z; acc.w += v.w;
    }
    __shared__ float4 lds[256];
    lds[t] = acc;
    __syncthreads();
    if (t < 32) {
        float4 s = lds[t];
        for (int k = 1; k < 8; ++k) {
            float4 v = lds[t + 32 * k];
            s.x += v.x; s.y += v.y; s.z += v.z; s.w += v.w;
        }
        float* dst = obs_sum + b * OBS + 4 * t;
        atomicAdd(dst + 0, s.x);
        atomicAdd(dst + 1, s.y);
        atomicAdd(dst + 2, s.z);
        atomicAdd(dst + 3, s.w);
    }
}

// ---------------- Pass 2 (after softmax): attention-weighted obs sum ----------------
__global__ void attn_sum_kernel(const float* __restrict__ obs,
                                const float* __restrict__ pn,   // priority_norm (in d_out)
                                float* __restrict__ att) {
    int blk = blockIdx.x;
    int b = blk / CHUNKS;
    int chunk = blk % CHUNKS;
    int t = threadIdx.x;
    int c4 = t & 31;
    int rg = t >> 5;
    const float4* obs4 = (const float4*)obs;
    size_t row0 = (size_t)b * PTS + (size_t)chunk * ROWS_PER_CHUNK;
    float4 acc = make_float4(0.f, 0.f, 0.f, 0.f);
    for (int r = rg; r < ROWS_PER_CHUNK; r += 8) {
        float w = pn[row0 + r];
        float4 v = obs4[(row0 + r) * (OBS / 4) + c4];
        acc.x = fmaf(v.x, w, acc.x);
        acc.y = fmaf(v.y, w, acc.y);
        acc.z = fmaf(v.z, w, acc.z);
        acc.w = fmaf(v.w, w, acc.w);
    }
    __shared__ float4 lds[256];
    lds[t] = acc;
    __syncthreads();
    if (t < 32) {
        float4 s = lds[t];
        for (int k = 1; k < 8; ++k) {
            float4 v = lds[t + 32 * k];
            s.x += v.x; s.y += v.y; s.z += v.z; s.w += v.w;
        }
        float* dst = att + b * OBS + 4 * t;
        atomicAdd(dst + 0, s.x);
        atomicAdd(dst + 1, s.y);
        atomicAdd(dst + 2, s.z);
        atomicAdd(dst + 3, s.w);
    }
}

// ---------------- GRU cell: one block per batch row, one thread per hidden unit ----------------
__global__ void gru_kernel(const float* __restrict__ action,
                           const float* __restrict__ coh_scalar,
                           const float* __restrict__ h_prev,
                           const float* __restrict__ z_prev,
                           const float* __restrict__ W_ih, const float* __restrict__ b_ih,
                           const float* __restrict__ W_hh, const float* __restrict__ b_hh,
                           float* __restrict__ out) {
    int b = blockIdx.x;
    int j = threadIdx.x;   // 0..255
    __shared__ float x[XIN];
    __shared__ float hp[HID];
    if (j < LAT)            x[j] = z_prev[b * LAT + j];
    else if (j < LAT + ACT) x[j] = action[b * ACT + (j - LAT)];
    else if (j == LAT + ACT) x[j] = coh_scalar[b];
    hp[j] = h_prev[b * HID + j];
    __syncthreads();

    float gi[3], gh[3];
#pragma unroll
    for (int g = 0; g < 3; ++g) {
        const float* wi = W_ih + (size_t)(g * HID + j) * XIN;
        float s = b_ih[g * HID + j];
        for (int k = 0; k < XIN; ++k) s = fmaf(wi[k], x[k], s);
        gi[g] = s;
        const float* wh = W_hh + (size_t)(g * HID + j) * HID;
        float s2 = b_hh[g * HID + j];
        for (int k = 0; k < HID; ++k) s2 = fmaf(wh[k], hp[k], s2);
        gh[g] = s2;
    }
    float r = 1.f / (1.f + expf(-(gi[0] + gh[0])));
    float u = 1.f / (1.f + expf(-(gi[1] + gh[1])));
    float n = tanhf(gi[2] + r * gh[2]);
    float h = (1.f - u) * n + u * hp[j];
    out[OFF_H + b * HID + j] = h;
}

// ---------------- Posterior head: post = [h, obs_agg] @ W_post^T + b; z, uncertainty ----------------
__global__ void post_kernel(const float* __restrict__ obs_sum,
                            const float* __restrict__ W_post, const float* __restrict__ b_post,
                            float* __restrict__ out) {
    int b = blockIdx.x;
    int j = threadIdx.x;   // 0..127
    __shared__ float cat[HID + OBS];   // 384
    cat[j]       = out[OFF_H + b * HID + j];
    cat[j + 128] = out[OFF_H + b * HID + j + 128];
    cat[HID + j] = obs_sum[b * OBS + j] * (1.0f / PTS);
    __syncthreads();
    const float* wr = W_post + (size_t)j * (HID + OBS);
    float s = b_post[j];
    for (int k = 0; k < HID + OBS; ++k) s = fmaf(wr[k], cat[k], s);
    if (j < LAT) out[OFF_Z + b * LAT + j] = s;   // z = mu_q
    __shared__ float lv[128];
    lv[j] = s;
    __syncthreads();
    if (j == 0) {
        float acc = 0.f;
        for (int k = 64; k < 128; ++k) acc += lv[k];   // sum logvar_q
        out[OFF_UNC + b] = 0.5f * (acc + (float)LAT * LOG2PIE);
    }
}

// ---------------- Per-segment softmax over priority; writes priority + priority_norm ----------------
__global__ void softmax_kernel(const float* __restrict__ coh_spatial,
                               float* __restrict__ out) {
    int b = blockIdx.x;
    int t = threadIdx.x;   // 0..255
    float u = out[OFF_UNC + b];
    __shared__ float sv[PTS];      // 16 KB
    __shared__ float red[256];
    int base = b * PTS;
    float lmax = -INFINITY;
    for (int i = t; i < PTS; i += 256) {
        float s = coh_spatial[base + i] * u;
        sv[i] = s;
        out[OFF_PRI + base + i] = s;   // TEMP = 1.0 -> priority == s
        lmax = fmaxf(lmax, s);
    }
    red[t] = lmax;
    __syncthreads();
    for (int off = 128; off > 0; off >>= 1) {
        if (t < off) red[t] = fmaxf(red[t], red[t + off]);
        __syncthreads();
    }
    float m = red[0];
    __syncthreads();
    float lsum = 0.f;
    for (int i = t; i < PTS; i += 256) {
        float e = expf(sv[i] - m);
        sv[i] = e;
        lsum += e;
    }
    red[t] = lsum;
    __syncthreads();
    for (int off = 128; off > 0; off >>= 1) {
        if (t < off) red[t] += red[t + off];
        __syncthreads();
    }
    float inv = 1.f / fmaxf(red[0], 1e-12f);
    __syncthreads();
    for (int i = t; i < PTS; i += 256) {
        out[OFF_PN + base + i] = sv[i] * inv;
    }
}

// ---------------- AE + context head: one block (512 threads) per batch row ----------------
__global__ void head_kernel(const float* __restrict__ att,
                            const float* __restrict__ W_ae1, const float* __restrict__ b_ae1,
                            const float* __restrict__ W_ae2, const float* __restrict__ b_ae2,
                            const float* __restrict__ W_c1,  const float* __restrict__ b_c1,
                            const float* __restrict__ W_c2,  const float* __restrict__ b_c2,
                            float* __restrict__ out) {
    int b = blockIdx.x;
    int t = threadIdx.x;   // 0..511
    __shared__ float ctxin[HID + LAT + OBS];   // 448: [h, z, obs_enc]
    __shared__ float a_lds[OBS];
    __shared__ float h1[256];
    __shared__ float c1[512];
    if (t < HID)                 ctxin[t] = out[OFF_H + b * HID + t];
    else if (t < HID + LAT)      ctxin[t] = out[OFF_Z + b * LAT + (t - HID)];
    else if (t < HID + LAT + OBS) a_lds[t - (HID + LAT)] = att[b * OBS + (t - (HID + LAT))];
    __syncthreads();
    if (t < 256) {
        const float* wr = W_ae1 + (size_t)t * OBS;
        float s = b_ae1[t];
        for (int k = 0; k < OBS; ++k) s = fmaf(wr[k], a_lds[k], s);
        h1[t] = fmaxf(s, 0.f);
    }
    __syncthreads();
    if (t < 128) {
        const float* wr = W_ae2 + (size_t)t * 256;
        float s = b_ae2[t];
        for (int k = 0; k < 256; ++k) s = fmaf(wr[k], h1[k], s);
        ctxin[HID + LAT + t] = s;   // obs_enc
    }
    __syncthreads();
    {
        const float* wr = W_c1 + (size_t)t * (HID + LAT + OBS);
        float s = b_c1[t];
        for (int k = 0; k < HID + LAT + OBS; ++k) s = fmaf(wr[k], ctxin[k], s);
        c1[t] = fmaxf(s, 0.f);
    }
    __syncthreads();
    if (t < CTX) {
        const float* wr = W_c2 + (size_t)t * 512;
        float s = b_c2[t];
        for (int k = 0; k < 512; ++k) s = fmaf(wr[k], c1[k], s);
        out[OFF_CTX + b * CTX + t] = s;
    }
}

extern "C" void kernel_launch(void* const* d_in, const int* in_sizes, int n_in,
                              void* d_out, int out_size, void* d_ws, size_t ws_size,
                              hipStream_t stream) {
    const float* obs         = (const float*)d_in[0];
    const float* action      = (const float*)d_in[1];
    const float* coh_scalar  = (const float*)d_in[2];
    const float* coh_spatial = (const float*)d_in[3];
    const float* h_prev      = (const float*)d_in[4];
    const float* z_prev      = (const float*)d_in[5];
    // d_in[6] = batch: structurally i >> 12 (contiguous segments) — not read.
    const float* W_ih   = (const float*)d_in[7];
    const float* b_ih   = (const float*)d_in[8];
    const float* W_hh   = (const float*)d_in[9];
    const float* b_hh   = (const float*)d_in[10];
    // d_in[11]/d_in[12] = W_prior/b_prior: dead (prior not in outputs).
    const float* W_post = (const float*)d_in[13];
    const float* b_post = (const float*)d_in[14];
    const float* W_ae1  = (const float*)d_in[15];
    const float* b_ae1  = (const float*)d_in[16];
    const float* W_ae2  = (const float*)d_in[17];
    const float* b_ae2  = (const float*)d_in[18];
    const float* W_c1   = (const float*)d_in[19];
    const float* b_c1   = (const float*)d_in[20];
    const float* W_c2   = (const float*)d_in[21];
    const float* b_c2   = (const float*)d_in[22];

    float* out = (float*)d_out;
    float* obs_sum = (float*)d_ws;             // BB*OBS floats
    float* att     = obs_sum + BB * OBS;       // BB*OBS floats

    // zero the two accumulator buffers (ws is poisoned 0xAA before every call)
    hipMemsetAsync(d_ws, 0, 2 * BB * OBS * sizeof(float), stream);

    seg_sum_kernel<<<BB * CHUNKS, 256, 0, stream>>>(obs, obs_sum);
    gru_kernel<<<BB, HID, 0, stream>>>(action, coh_scalar, h_prev, z_prev,
                                       W_ih, b_ih, W_hh, b_hh, out);
    post_kernel<<<BB, 128, 0, stream>>>(obs_sum, W_post, b_post, out);
    softmax_kernel<<<BB, 256, 0, stream>>>(coh_spatial, out);
    attn_sum_kernel<<<BB * CHUNKS, 256, 0, stream>>>(obs, out + OFF_PN, att);
    head_kernel<<<BB, 512, 0, stream>>>(att, W_ae1, b_ae1, W_ae2, b_ae2,
                                        W_c1, b_c1, W_c2, b_c2, out);
}